// Round 1
// baseline (1572.870 us; speedup 1.0000x reference)
//
#include <hip/hip_runtime.h>

#define T_TOK 8192
#define DDIM 1024
#define IDIM 2048
#define NEXP 8
#define BK 32
#define LDB 40  // padded LDS row length (ushorts): 80B rows -> conflict-free frag reads

typedef short bf16x8 __attribute__((ext_vector_type(8)));
typedef float f32x4 __attribute__((ext_vector_type(4)));

__device__ __forceinline__ unsigned short f2bf(float f) {
  union { float f; unsigned int u; } v; v.f = f;
  unsigned int r = v.u + 0x7fffu + ((v.u >> 16) & 1u);
  return (unsigned short)(r >> 16);
}

__device__ __forceinline__ unsigned int pack2bf(float lo, float hi) {
  return (unsigned int)f2bf(lo) | ((unsigned int)f2bf(hi) << 16);
}

// ---------------- x -> bf16 ----------------
__global__ __launch_bounds__(256) void convert_kernel(const float* __restrict__ x,
                                                      ushort* __restrict__ xb, int n4) {
  int i = blockIdx.x * 256 + threadIdx.x;
  if (i >= n4) return;
  float4 v = ((const float4*)x)[i];
  ushort4 o;
  o.x = f2bf(v.x); o.y = f2bf(v.y); o.z = f2bf(v.z); o.w = f2bf(v.w);
  ((ushort4*)xb)[i] = o;
}

// ---------------- router: top-2 + expert lists ----------------
__global__ __launch_bounds__(256) void router_kernel(
    const float* __restrict__ x, const float* __restrict__ rw, const float* __restrict__ rb,
    int* __restrict__ cnt, int* __restrict__ lists, float* __restrict__ wts) {
  const int token = blockIdx.x * 4 + (threadIdx.x >> 6);
  const int lane = threadIdx.x & 63;
  float acc[NEXP];
#pragma unroll
  for (int e = 0; e < NEXP; ++e) acc[e] = 0.f;
  const float* xr = x + (size_t)token * DDIM;
#pragma unroll
  for (int j = 0; j < DDIM / 64; ++j) {
    int d = j * 64 + lane;
    float xv = xr[d];
    const float4* w = (const float4*)(rw + d * NEXP);
    float4 w0 = w[0], w1 = w[1];
    acc[0] += xv * w0.x; acc[1] += xv * w0.y; acc[2] += xv * w0.z; acc[3] += xv * w0.w;
    acc[4] += xv * w1.x; acc[5] += xv * w1.y; acc[6] += xv * w1.z; acc[7] += xv * w1.w;
  }
#pragma unroll
  for (int e = 0; e < NEXP; ++e) {
    float v = acc[e];
    for (int off = 32; off > 0; off >>= 1) v += __shfl_xor(v, off, 64);
    acc[e] = v;
  }
  if (lane == 0) {
    float l[NEXP];
#pragma unroll
    for (int e = 0; e < NEXP; ++e) l[e] = acc[e] + rb[e];
    int i0 = 0; float b0 = l[0];
#pragma unroll
    for (int e = 1; e < NEXP; ++e) if (l[e] > b0) { b0 = l[e]; i0 = e; }
    int i1 = -1; float b1 = -3.0e38f;
#pragma unroll
    for (int e = 0; e < NEXP; ++e) if (e != i0 && l[e] > b1) { b1 = l[e]; i1 = e; }
    // renormalized top-2 softmax == softmax over the two logits
    float e1 = expf(b1 - b0);
    float inv = 1.f / (1.f + e1);
    wts[token * 2 + 0] = inv;
    wts[token * 2 + 1] = e1 * inv;
    int s0 = atomicAdd(&cnt[i0], 1);
    lists[i0 * T_TOK + s0] = token * 2;
    int s1 = atomicAdd(&cnt[i1], 1);
    lists[i1 * T_TOK + s1] = token * 2 + 1;
  }
}

// ---------------- GEMM1: h = silu(x@gate_w+b) * (x@up_w+b), gathered rows ----------------
__global__ __launch_bounds__(256, 2) void gemm1_kernel(
    const ushort* __restrict__ xb,
    const float* __restrict__ gate_w, const float* __restrict__ gate_b,
    const float* __restrict__ up_w, const float* __restrict__ up_b,
    const int* __restrict__ lists, const int* __restrict__ cnt,
    ushort* __restrict__ hbuf) {
  const int e = blockIdx.z;
  const int ce = cnt[e];
  const int m0 = blockIdx.x * 128;
  if (m0 >= ce) return;
  const int n0 = blockIdx.y * 128;

  __shared__ __align__(16) ushort As[128 * LDB];
  __shared__ __align__(16) ushort Bg[128 * LDB];
  __shared__ __align__(16) ushort Bu[128 * LDB];
  __shared__ int rowinfo[128];

  const int tid = threadIdx.x;
  if (tid < 128) {
    int slot = m0 + tid;
    rowinfo[tid] = lists[e * T_TOK + (slot < ce ? slot : 0)];
  }
  __syncthreads();

  // A staging: 128 rows x 32 bf16; thread -> (row, 8-elem quarter), 2 rows apart
  const int ar0 = tid >> 2;
  const int ar1 = ar0 + 64;
  const int aq = (tid & 3) * 8;
  const ushort* asrc0 = xb + (size_t)(rowinfo[ar0] >> 1) * DDIM + aq;
  const ushort* asrc1 = xb + (size_t)(rowinfo[ar1] >> 1) * DDIM + aq;
  ushort* adst0 = &As[ar0 * LDB + aq];
  ushort* adst1 = &As[ar1 * LDB + aq];

  // B staging: thread -> col-group bc..bc+7, k-pair bkp/bkp+1 (transpose into [n][k])
  const int bc = (tid >> 4) * 8;
  const int bkp = (tid & 15) * 2;
  const size_t wbase = (size_t)e * DDIM * IDIM + (size_t)bkp * IDIM + n0 + bc;
  const float* gsrc = gate_w + wbase;
  const float* usrc = up_w + wbase;
  unsigned int* Bg32 = (unsigned int*)Bg;
  unsigned int* Bu32 = (unsigned int*)Bu;
  const int bdst = bc * (LDB / 2) + (bkp >> 1);

  const int lane = tid & 63;
  const int wave = tid >> 6;
  const int fm = lane & 15;
  const int fq = lane >> 4;
  const int wm = wave * 32;

  f32x4 accg[2][8], accu[2][8];
  const f32x4 zero4 = {0.f, 0.f, 0.f, 0.f};
#pragma unroll
  for (int i = 0; i < 2; ++i)
#pragma unroll
    for (int j = 0; j < 8; ++j) { accg[i][j] = zero4; accu[i][j] = zero4; }

#pragma unroll 1
  for (int k0 = 0; k0 < DDIM; k0 += BK) {
    __syncthreads();
    *(uint4*)adst0 = *(const uint4*)(asrc0 + k0);
    *(uint4*)adst1 = *(const uint4*)(asrc1 + k0);
    {
      const float* p0 = gsrc + (size_t)k0 * IDIM;
      const float* p1 = p0 + IDIM;
      float4 x0 = ((const float4*)p0)[0];
      float4 x1 = ((const float4*)p0)[1];
      float4 y0 = ((const float4*)p1)[0];
      float4 y1 = ((const float4*)p1)[1];
      Bg32[bdst + 0 * (LDB / 2)] = pack2bf(x0.x, y0.x);
      Bg32[bdst + 1 * (LDB / 2)] = pack2bf(x0.y, y0.y);
      Bg32[bdst + 2 * (LDB / 2)] = pack2bf(x0.z, y0.z);
      Bg32[bdst + 3 * (LDB / 2)] = pack2bf(x0.w, y0.w);
      Bg32[bdst + 4 * (LDB / 2)] = pack2bf(x1.x, y1.x);
      Bg32[bdst + 5 * (LDB / 2)] = pack2bf(x1.y, y1.y);
      Bg32[bdst + 6 * (LDB / 2)] = pack2bf(x1.z, y1.z);
      Bg32[bdst + 7 * (LDB / 2)] = pack2bf(x1.w, y1.w);
      const float* q0 = usrc + (size_t)k0 * IDIM;
      const float* q1 = q0 + IDIM;
      x0 = ((const float4*)q0)[0];
      x1 = ((const float4*)q0)[1];
      y0 = ((const float4*)q1)[0];
      y1 = ((const float4*)q1)[1];
      Bu32[bdst + 0 * (LDB / 2)] = pack2bf(x0.x, y0.x);
      Bu32[bdst + 1 * (LDB / 2)] = pack2bf(x0.y, y0.y);
      Bu32[bdst + 2 * (LDB / 2)] = pack2bf(x0.z, y0.z);
      Bu32[bdst + 3 * (LDB / 2)] = pack2bf(x0.w, y0.w);
      Bu32[bdst + 4 * (LDB / 2)] = pack2bf(x1.x, y1.x);
      Bu32[bdst + 5 * (LDB / 2)] = pack2bf(x1.y, y1.y);
      Bu32[bdst + 6 * (LDB / 2)] = pack2bf(x1.z, y1.z);
      Bu32[bdst + 7 * (LDB / 2)] = pack2bf(x1.w, y1.w);
    }
    __syncthreads();
    bf16x8 a0 = *(const bf16x8*)&As[(wm + fm) * LDB + fq * 8];
    bf16x8 a1 = *(const bf16x8*)&As[(wm + 16 + fm) * LDB + fq * 8];
#pragma unroll
    for (int nf = 0; nf < 8; ++nf) {
      bf16x8 bg = *(const bf16x8*)&Bg[(nf * 16 + fm) * LDB + fq * 8];
      bf16x8 bu = *(const bf16x8*)&Bu[(nf * 16 + fm) * LDB + fq * 8];
      accg[0][nf] = __builtin_amdgcn_mfma_f32_16x16x32_bf16(a0, bg, accg[0][nf], 0, 0, 0);
      accg[1][nf] = __builtin_amdgcn_mfma_f32_16x16x32_bf16(a1, bg, accg[1][nf], 0, 0, 0);
      accu[0][nf] = __builtin_amdgcn_mfma_f32_16x16x32_bf16(a0, bu, accu[0][nf], 0, 0, 0);
      accu[1][nf] = __builtin_amdgcn_mfma_f32_16x16x32_bf16(a1, bu, accu[1][nf], 0, 0, 0);
    }
  }

#pragma unroll
  for (int nf = 0; nf < 8; ++nf) {
    const int col = n0 + nf * 16 + fm;
    const float gbias = gate_b[e * IDIM + col];
    const float ubias = up_b[e * IDIM + col];
#pragma unroll
    for (int mf = 0; mf < 2; ++mf) {
#pragma unroll
      for (int r = 0; r < 4; ++r) {
        const int row = wm + mf * 16 + fq * 4 + r;
        if (m0 + row < ce) {
          const int packed = rowinfo[row];
          float g = accg[mf][nf][r] + gbias;
          float u = accu[mf][nf][r] + ubias;
          float h = g * (1.f / (1.f + __expf(-g))) * u;
          hbuf[(size_t)packed * IDIM + col] = f2bf(h);
        }
      }
    }
  }
}

// ---------------- GEMM2: out += w * (h @ down_w + down_b) ----------------
__global__ __launch_bounds__(256, 2) void gemm2_kernel(
    const ushort* __restrict__ hbuf,
    const float* __restrict__ down_w, const float* __restrict__ down_b,
    const int* __restrict__ lists, const int* __restrict__ cnt,
    const float* __restrict__ wts, float* __restrict__ out) {
  const int e = blockIdx.z;
  const int ce = cnt[e];
  const int m0 = blockIdx.x * 128;
  if (m0 >= ce) return;
  const int n0 = blockIdx.y * 128;

  __shared__ __align__(16) ushort As[128 * LDB];
  __shared__ __align__(16) ushort Bs[128 * LDB];
  __shared__ int rowinfo[128];

  const int tid = threadIdx.x;
  if (tid < 128) {
    int slot = m0 + tid;
    rowinfo[tid] = lists[e * T_TOK + (slot < ce ? slot : 0)];
  }
  __syncthreads();

  const int ar0 = tid >> 2;
  const int ar1 = ar0 + 64;
  const int aq = (tid & 3) * 8;
  const ushort* asrc0 = hbuf + (size_t)rowinfo[ar0] * IDIM + aq;
  const ushort* asrc1 = hbuf + (size_t)rowinfo[ar1] * IDIM + aq;
  ushort* adst0 = &As[ar0 * LDB + aq];
  ushort* adst1 = &As[ar1 * LDB + aq];

  const int bc = (tid >> 4) * 8;
  const int bkp = (tid & 15) * 2;
  const float* bsrc = down_w + (size_t)e * IDIM * DDIM + (size_t)bkp * DDIM + n0 + bc;
  unsigned int* Bs32 = (unsigned int*)Bs;
  const int bdst = bc * (LDB / 2) + (bkp >> 1);

  const int lane = tid & 63;
  const int wave = tid >> 6;
  const int fm = lane & 15;
  const int fq = lane >> 4;
  const int wm = wave * 32;

  f32x4 acc[2][8];
  const f32x4 zero4 = {0.f, 0.f, 0.f, 0.f};
#pragma unroll
  for (int i = 0; i < 2; ++i)
#pragma unroll
    for (int j = 0; j < 8; ++j) acc[i][j] = zero4;

#pragma unroll 1
  for (int k0 = 0; k0 < IDIM; k0 += BK) {
    __syncthreads();
    *(uint4*)adst0 = *(const uint4*)(asrc0 + k0);
    *(uint4*)adst1 = *(const uint4*)(asrc1 + k0);
    {
      const float* p0 = bsrc + (size_t)k0 * DDIM;
      const float* p1 = p0 + DDIM;
      float4 x0 = ((const float4*)p0)[0];
      float4 x1 = ((const float4*)p0)[1];
      float4 y0 = ((const float4*)p1)[0];
      float4 y1 = ((const float4*)p1)[1];
      Bs32[bdst + 0 * (LDB / 2)] = pack2bf(x0.x, y0.x);
      Bs32[bdst + 1 * (LDB / 2)] = pack2bf(x0.y, y0.y);
      Bs32[bdst + 2 * (LDB / 2)] = pack2bf(x0.z, y0.z);
      Bs32[bdst + 3 * (LDB / 2)] = pack2bf(x0.w, y0.w);
      Bs32[bdst + 4 * (LDB / 2)] = pack2bf(x1.x, y1.x);
      Bs32[bdst + 5 * (LDB / 2)] = pack2bf(x1.y, y1.y);
      Bs32[bdst + 6 * (LDB / 2)] = pack2bf(x1.z, y1.z);
      Bs32[bdst + 7 * (LDB / 2)] = pack2bf(x1.w, y1.w);
    }
    __syncthreads();
    bf16x8 a0 = *(const bf16x8*)&As[(wm + fm) * LDB + fq * 8];
    bf16x8 a1 = *(const bf16x8*)&As[(wm + 16 + fm) * LDB + fq * 8];
#pragma unroll
    for (int nf = 0; nf < 8; ++nf) {
      bf16x8 b = *(const bf16x8*)&Bs[(nf * 16 + fm) * LDB + fq * 8];
      acc[0][nf] = __builtin_amdgcn_mfma_f32_16x16x32_bf16(a0, b, acc[0][nf], 0, 0, 0);
      acc[1][nf] = __builtin_amdgcn_mfma_f32_16x16x32_bf16(a1, b, acc[1][nf], 0, 0, 0);
    }
  }

#pragma unroll
  for (int nf = 0; nf < 8; ++nf) {
    const int col = n0 + nf * 16 + fm;
    const float dbias = down_b[e * DDIM + col];
#pragma unroll
    for (int mf = 0; mf < 2; ++mf) {
#pragma unroll
      for (int r = 0; r < 4; ++r) {
        const int row = wm + mf * 16 + fq * 4 + r;
        if (m0 + row < ce) {
          const int packed = rowinfo[row];
          const float w = wts[packed];
          const int token = packed >> 1;
          atomicAdd(&out[(size_t)token * DDIM + col], w * (acc[mf][nf][r] + dbias));
        }
      }
    }
  }
}

extern "C" void kernel_launch(void* const* d_in, const int* in_sizes, int n_in,
                              void* d_out, int out_size, void* d_ws, size_t ws_size,
                              hipStream_t stream) {
  const float* x = (const float*)d_in[0];
  const float* rw = (const float*)d_in[1];
  const float* rb = (const float*)d_in[2];
  const float* gw = (const float*)d_in[3];
  const float* gb = (const float*)d_in[4];
  const float* uw = (const float*)d_in[5];
  const float* ub = (const float*)d_in[6];
  const float* dw = (const float*)d_in[7];
  const float* db = (const float*)d_in[8];
  float* out = (float*)d_out;

  char* ws = (char*)d_ws;
  ushort* xb = (ushort*)ws;                                   // 16 MB
  ushort* hbuf = (ushort*)(ws + 16777216);                    // 64 MB
  float* wts = (float*)(ws + 16777216 + 67108864);            // 64 KB
  int* lists = (int*)(ws + 16777216 + 67108864 + 65536);      // 256 KB
  int* cnt = (int*)(ws + 16777216 + 67108864 + 65536 + 262144);

  hipMemsetAsync(cnt, 0, NEXP * sizeof(int), stream);
  hipMemsetAsync(out, 0, (size_t)out_size * sizeof(float), stream);

  convert_kernel<<<(T_TOK * DDIM / 4 + 255) / 256, 256, 0, stream>>>(x, xb, T_TOK * DDIM / 4);
  router_kernel<<<T_TOK / 4, 256, 0, stream>>>(x, rw, rb, cnt, lists, wts);
  gemm1_kernel<<<dim3(T_TOK / 128, IDIM / 128, NEXP), 256, 0, stream>>>(xb, gw, gb, uw, ub, lists, cnt, hbuf);
  gemm2_kernel<<<dim3(T_TOK / 128, DDIM / 128, NEXP), 256, 0, stream>>>(hbuf, dw, db, lists, cnt, wts, out);
}

// Round 2
// 1046.404 us; speedup vs baseline: 1.5031x; 1.5031x over previous
//
#include <hip/hip_runtime.h>

#define T_TOK 8192
#define DDIM 1024
#define IDIM 2048
#define NEXP 8

typedef short bf16x8 __attribute__((ext_vector_type(8)));
typedef float f32x4 __attribute__((ext_vector_type(4)));

__device__ __forceinline__ unsigned short f2bf(float f) {
  union { float f; unsigned int u; } v; v.f = f;
  unsigned int r = v.u + 0x7fffu + ((v.u >> 16) & 1u);
  return (unsigned short)(r >> 16);
}

typedef const __attribute__((address_space(1))) void* gas_t;
typedef __attribute__((address_space(3))) void* las_t;
__device__ __forceinline__ void async_copy16(void* lds, const void* g) {
  __builtin_amdgcn_global_load_lds((gas_t)g, (las_t)lds, 16, 0, 0);
}

// ---------------- x -> bf16 ----------------
__global__ __launch_bounds__(256) void convert_kernel(const float* __restrict__ x,
                                                      ushort* __restrict__ xb, int n4) {
  int i = blockIdx.x * 256 + threadIdx.x;
  if (i >= n4) return;
  float4 v = ((const float4*)x)[i];
  ushort4 o;
  o.x = f2bf(v.x); o.y = f2bf(v.y); o.z = f2bf(v.z); o.w = f2bf(v.w);
  ((ushort4*)xb)[i] = o;
}

// ---------------- transpose + convert: src[e][R][C] f32 -> dst[e][C'][R] bf16 ----------------
// interleave=1 (gate/up): dst row for col i is (i>>6)*128 + sel*64 + (i&63)
__global__ __launch_bounds__(256) void tconv_kernel(
    const float* __restrict__ src, ushort* __restrict__ dst, int R, int C,
    int sel, int interleave, size_t srcEStride, size_t dstEStride) {
  const int e = blockIdx.z;
  const float* s = src + (size_t)e * srcEStride;
  ushort* d = dst + (size_t)e * dstEStride;
  const int c0 = blockIdx.x * 64, r0 = blockIdx.y * 64;
  const int t = threadIdx.x;
  const int str = t >> 4, stc = t & 15;
  const int rr = r0 + 4 * str, cc = c0 + 4 * stc;
  float4 v[4];
#pragma unroll
  for (int j = 0; j < 4; ++j)
    v[j] = *(const float4*)(s + (size_t)(rr + j) * C + cc);
#pragma unroll
  for (int jc = 0; jc < 4; ++jc) {
    int ci = cc + jc;
    int drow = interleave ? ((ci >> 6) * 128 + sel * 64 + (ci & 63)) : ci;
    ushort4 o;
    o.x = f2bf(((const float*)&v[0])[jc]);
    o.y = f2bf(((const float*)&v[1])[jc]);
    o.z = f2bf(((const float*)&v[2])[jc]);
    o.w = f2bf(((const float*)&v[3])[jc]);
    *(ushort4*)(d + (size_t)drow * R + rr) = o;
  }
}

// ---------------- router: top-2 + expert lists ----------------
__global__ __launch_bounds__(256) void router_kernel(
    const float* __restrict__ x, const float* __restrict__ rw, const float* __restrict__ rb,
    int* __restrict__ cnt, int* __restrict__ lists, float* __restrict__ wts) {
  const int token = blockIdx.x * 4 + (threadIdx.x >> 6);
  const int lane = threadIdx.x & 63;
  float acc[NEXP];
#pragma unroll
  for (int e = 0; e < NEXP; ++e) acc[e] = 0.f;
  const float* xr = x + (size_t)token * DDIM;
#pragma unroll
  for (int j = 0; j < DDIM / 64; ++j) {
    int d = j * 64 + lane;
    float xv = xr[d];
    const float4* w = (const float4*)(rw + d * NEXP);
    float4 w0 = w[0], w1 = w[1];
    acc[0] += xv * w0.x; acc[1] += xv * w0.y; acc[2] += xv * w0.z; acc[3] += xv * w0.w;
    acc[4] += xv * w1.x; acc[5] += xv * w1.y; acc[6] += xv * w1.z; acc[7] += xv * w1.w;
  }
#pragma unroll
  for (int e = 0; e < NEXP; ++e) {
    float v = acc[e];
    for (int off = 32; off > 0; off >>= 1) v += __shfl_xor(v, off, 64);
    acc[e] = v;
  }
  if (lane == 0) {
    float l[NEXP];
#pragma unroll
    for (int e = 0; e < NEXP; ++e) l[e] = acc[e] + rb[e];
    int i0 = 0; float b0 = l[0];
#pragma unroll
    for (int e = 1; e < NEXP; ++e) if (l[e] > b0) { b0 = l[e]; i0 = e; }
    int i1 = -1; float b1 = -3.0e38f;
#pragma unroll
    for (int e = 0; e < NEXP; ++e) if (e != i0 && l[e] > b1) { b1 = l[e]; i1 = e; }
    float e1 = expf(b1 - b0);
    float inv = 1.f / (1.f + e1);
    wts[token * 2 + 0] = inv;
    wts[token * 2 + 1] = e1 * inv;
    int s0 = atomicAdd(&cnt[i0], 1);
    lists[i0 * T_TOK + s0] = token * 2;
    int s1 = atomicAdd(&cnt[i1], 1);
    lists[i1 * T_TOK + s1] = token * 2 + 1;
  }
}

// ---------------- GEMM1: fused gate/up, m97-style, 128x128 tile, BK=64 ----------------
// wcat[e]: 4096 rows x 1024 (bf16): rows 128t..128t+63 = gate^T cols 64t.., +64..+127 = up^T
__global__ __launch_bounds__(256, 2) void gemm1_kernel(
    const ushort* __restrict__ xb, const ushort* __restrict__ wcat,
    const float* __restrict__ gate_b, const float* __restrict__ up_b,
    const int* __restrict__ lists, const int* __restrict__ cnt,
    ushort* __restrict__ hbuf) {
  const int e = blockIdx.z;
  const int ce = cnt[e];
  const int m0 = blockIdx.x * 128;
  if (m0 >= ce) return;
  const int by = blockIdx.y;  // 0..31 -> cols 64*by .. +63 (gate & up)

  __shared__ __align__(16) ushort smem[2 * 128 * 64];  // As | Bs, 32 KB
  __shared__ int rowinfo[128];
  ushort* As = smem;
  ushort* Bs = smem + 128 * 64;

  const int tid = threadIdx.x;
  if (tid < 128) {
    int slot = m0 + tid;
    rowinfo[tid] = lists[e * T_TOK + (slot < ce ? slot : 0)];
  }
  __syncthreads();

  const int w = tid >> 6, lane = tid & 63;
  const int fm = lane & 15, fq = lane >> 4;
  const int waveM = w >> 1, waveN = w & 1;
  const int lr = lane >> 3;                       // row-in-group 0..7
  const int lchunk = ((lane & 7) ^ lr) * 8;       // XOR-swizzled 16B chunk (ushort units)

  const ushort* wcatE = wcat + (size_t)e * 4096 * 1024;
  const ushort* aG[4]; const ushort* bG[4];
  ushort* aL[4]; ushort* bL[4];
#pragma unroll
  for (int j = 0; j < 4; ++j) {
    int rl = 32 * w + 8 * j + lr;
    aG[j] = xb + (size_t)(rowinfo[rl] >> 1) * DDIM + lchunk;
    bG[j] = wcatE + (size_t)(128 * by + rl) * DDIM + lchunk;
    aL[j] = As + (32 * w + 8 * j) * 64;
    bL[j] = Bs + (32 * w + 8 * j) * 64;
  }

  f32x4 acc[4][4];
  const f32x4 zero4 = {0.f, 0.f, 0.f, 0.f};
#pragma unroll
  for (int i = 0; i < 4; ++i)
#pragma unroll
    for (int j = 0; j < 4; ++j) acc[i][j] = zero4;

#pragma unroll 1
  for (int kt = 0; kt < DDIM / 64; ++kt) {
    __syncthreads();
#pragma unroll
    for (int j = 0; j < 4; ++j) {
      async_copy16(aL[j], aG[j] + kt * 64);
      async_copy16(bL[j], bG[j] + kt * 64);
    }
    __syncthreads();
#pragma unroll
    for (int ks = 0; ks < 2; ++ks) {
      bf16x8 af[4], bfr[4];
#pragma unroll
      for (int mf = 0; mf < 4; ++mf) {
        int row = 64 * waveM + 16 * mf + fm;
        af[mf] = *(const bf16x8*)&As[row * 64 + (((ks * 4 + fq) ^ (fm & 7)) * 8)];
      }
#pragma unroll
      for (int nf = 0; nf < 4; ++nf) {
        int row = 64 * waveN + 16 * nf + fm;
        bfr[nf] = *(const bf16x8*)&Bs[row * 64 + (((ks * 4 + fq) ^ (fm & 7)) * 8)];
      }
#pragma unroll
      for (int mf = 0; mf < 4; ++mf)
#pragma unroll
        for (int nf = 0; nf < 4; ++nf)
          acc[mf][nf] = __builtin_amdgcn_mfma_f32_16x16x32_bf16(af[mf], bfr[nf], acc[mf][nf], 0, 0, 0);
    }
  }

  // epilogue: up-waves (waveN=1) publish u via LDS; gate-waves fuse silu(g)*u
  __syncthreads();
  float* uld = (float*)smem;  // [128][64] fp32 = 32 KB
  if (waveN == 1) {
#pragma unroll
    for (int mf = 0; mf < 4; ++mf)
#pragma unroll
      for (int nf = 0; nf < 4; ++nf)
#pragma unroll
        for (int r = 0; r < 4; ++r)
          uld[(64 * waveM + 16 * mf + 4 * fq + r) * 64 + 16 * nf + fm] = acc[mf][nf][r];
  }
  __syncthreads();
  if (waveN == 0) {
#pragma unroll
    for (int nf = 0; nf < 4; ++nf) {
      const int col = 64 * by + 16 * nf + fm;
      const float gbias = gate_b[e * IDIM + col];
      const float ubias = up_b[e * IDIM + col];
#pragma unroll
      for (int mf = 0; mf < 4; ++mf) {
#pragma unroll
        for (int r = 0; r < 4; ++r) {
          const int row = 64 * waveM + 16 * mf + 4 * fq + r;
          if (m0 + row < ce) {
            const int packed = rowinfo[row];
            float g = acc[mf][nf][r] + gbias;
            float u = uld[row * 64 + 16 * nf + fm] + ubias;
            float h = g * (1.f / (1.f + __expf(-g))) * u;
            hbuf[(size_t)packed * IDIM + col] = f2bf(h);
          }
        }
      }
    }
  }
}

// ---------------- GEMM2: out += w * (h @ down_w + down_b), m97-style ----------------
__global__ __launch_bounds__(256, 2) void gemm2_kernel(
    const ushort* __restrict__ hbuf, const ushort* __restrict__ downT,
    const float* __restrict__ down_b,
    const int* __restrict__ lists, const int* __restrict__ cnt,
    const float* __restrict__ wts, float* __restrict__ out) {
  const int e = blockIdx.z;
  const int ce = cnt[e];
  const int m0 = blockIdx.x * 128;
  if (m0 >= ce) return;
  const int by = blockIdx.y;  // 0..7 -> out cols 128*by..

  __shared__ __align__(16) ushort smem[2 * 128 * 64];
  __shared__ int rowinfo[128];
  ushort* As = smem;
  ushort* Bs = smem + 128 * 64;

  const int tid = threadIdx.x;
  if (tid < 128) {
    int slot = m0 + tid;
    rowinfo[tid] = lists[e * T_TOK + (slot < ce ? slot : 0)];
  }
  __syncthreads();

  const int w = tid >> 6, lane = tid & 63;
  const int fm = lane & 15, fq = lane >> 4;
  const int waveM = w >> 1, waveN = w & 1;
  const int lr = lane >> 3;
  const int lchunk = ((lane & 7) ^ lr) * 8;

  const ushort* downE = downT + (size_t)e * DDIM * IDIM;
  const ushort* aG[4]; const ushort* bG[4];
  ushort* aL[4]; ushort* bL[4];
#pragma unroll
  for (int j = 0; j < 4; ++j) {
    int rl = 32 * w + 8 * j + lr;
    aG[j] = hbuf + (size_t)rowinfo[rl] * IDIM + lchunk;
    bG[j] = downE + (size_t)(128 * by + rl) * IDIM + lchunk;
    aL[j] = As + (32 * w + 8 * j) * 64;
    bL[j] = Bs + (32 * w + 8 * j) * 64;
  }

  f32x4 acc[4][4];
  const f32x4 zero4 = {0.f, 0.f, 0.f, 0.f};
#pragma unroll
  for (int i = 0; i < 4; ++i)
#pragma unroll
    for (int j = 0; j < 4; ++j) acc[i][j] = zero4;

#pragma unroll 1
  for (int kt = 0; kt < IDIM / 64; ++kt) {
    __syncthreads();
#pragma unroll
    for (int j = 0; j < 4; ++j) {
      async_copy16(aL[j], aG[j] + kt * 64);
      async_copy16(bL[j], bG[j] + kt * 64);
    }
    __syncthreads();
#pragma unroll
    for (int ks = 0; ks < 2; ++ks) {
      bf16x8 af[4], bfr[4];
#pragma unroll
      for (int mf = 0; mf < 4; ++mf) {
        int row = 64 * waveM + 16 * mf + fm;
        af[mf] = *(const bf16x8*)&As[row * 64 + (((ks * 4 + fq) ^ (fm & 7)) * 8)];
      }
#pragma unroll
      for (int nf = 0; nf < 4; ++nf) {
        int row = 64 * waveN + 16 * nf + fm;
        bfr[nf] = *(const bf16x8*)&Bs[row * 64 + (((ks * 4 + fq) ^ (fm & 7)) * 8)];
      }
#pragma unroll
      for (int mf = 0; mf < 4; ++mf)
#pragma unroll
        for (int nf = 0; nf < 4; ++nf)
          acc[mf][nf] = __builtin_amdgcn_mfma_f32_16x16x32_bf16(af[mf], bfr[nf], acc[mf][nf], 0, 0, 0);
    }
  }

#pragma unroll
  for (int nf = 0; nf < 4; ++nf) {
    const int col = 128 * by + 64 * waveN + 16 * nf + fm;
    const float dbias = down_b[e * DDIM + col];
#pragma unroll
    for (int mf = 0; mf < 4; ++mf) {
#pragma unroll
      for (int r = 0; r < 4; ++r) {
        const int row = 64 * waveM + 16 * mf + 4 * fq + r;
        if (m0 + row < ce) {
          const int packed = rowinfo[row];
          const float wt = wts[packed];
          const int token = packed >> 1;
          atomicAdd(&out[(size_t)token * DDIM + col], wt * (acc[mf][nf][r] + dbias));
        }
      }
    }
  }
}

extern "C" void kernel_launch(void* const* d_in, const int* in_sizes, int n_in,
                              void* d_out, int out_size, void* d_ws, size_t ws_size,
                              hipStream_t stream) {
  const float* x = (const float*)d_in[0];
  const float* rw = (const float*)d_in[1];
  const float* rb = (const float*)d_in[2];
  const float* gw = (const float*)d_in[3];
  const float* gb = (const float*)d_in[4];
  const float* uw = (const float*)d_in[5];
  const float* ub = (const float*)d_in[6];
  const float* dw = (const float*)d_in[7];
  const float* db = (const float*)d_in[8];
  float* out = (float*)d_out;

  char* ws = (char*)d_ws;
  ushort* xb    = (ushort*)(ws);                              // 16 MB
  ushort* hbuf  = (ushort*)(ws + (16ull << 20));              // 64 MB
  ushort* wcat  = (ushort*)(ws + (80ull << 20));              // 64 MB
  ushort* downT = (ushort*)(ws + (144ull << 20));             // 32 MB
  float*  wts   = (float*) (ws + (176ull << 20));             // 64 KB
  int*    lists = (int*)   (ws + (176ull << 20) + 65536);     // 256 KB
  int*    cnt   = (int*)   (ws + (176ull << 20) + 65536 + 262144);

  hipMemsetAsync(cnt, 0, NEXP * sizeof(int), stream);
  hipMemsetAsync(out, 0, (size_t)out_size * sizeof(float), stream);

  convert_kernel<<<(T_TOK * DDIM / 4 + 255) / 256, 256, 0, stream>>>(x, xb, T_TOK * DDIM / 4);
  router_kernel<<<T_TOK / 4, 256, 0, stream>>>(x, rw, rb, cnt, lists, wts);
  // gate/up -> wcat (interleaved 64-col halves), down -> downT
  tconv_kernel<<<dim3(IDIM / 64, DDIM / 64, NEXP), 256, 0, stream>>>(
      gw, wcat, DDIM, IDIM, 0, 1, (size_t)DDIM * IDIM, (size_t)2 * IDIM * DDIM);
  tconv_kernel<<<dim3(IDIM / 64, DDIM / 64, NEXP), 256, 0, stream>>>(
      uw, wcat, DDIM, IDIM, 1, 1, (size_t)DDIM * IDIM, (size_t)2 * IDIM * DDIM);
  tconv_kernel<<<dim3(DDIM / 64, IDIM / 64, NEXP), 256, 0, stream>>>(
      dw, downT, IDIM, DDIM, 0, 0, (size_t)IDIM * DDIM, (size_t)DDIM * IDIM);

  gemm1_kernel<<<dim3(T_TOK / 128, IDIM / 64, NEXP), 256, 0, stream>>>(
      xb, wcat, gb, ub, lists, cnt, hbuf);
  gemm2_kernel<<<dim3(T_TOK / 128, DDIM / 128, NEXP), 256, 0, stream>>>(
      hbuf, downT, db, lists, cnt, wts, out);
}